// Round 2
// baseline (635.325 us; speedup 1.0000x reference)
//
#include <hip/hip_runtime.h>
#include <hip/hip_fp16.h>

#define TT 100
#define BB 4096
#define GSTRIDE 388   // doubles per group blob; 776 words, %32 = 8 -> bank stagger

// per-group layout (in doubles):
//   V   [0,144)    value matrix 12x12, bitwise symmetric
//   S   [144,288)  symmetrize scratch 12x12  (aliased: Fl = float[12][20] in same bytes)
//   Qxu [288,336)  Qxu[r*12+i] = Q[i][12+r]
//   Quu [336,352)  col-major 4x4
//   vv  [352,364)  v vector
//   tb  [364,380)  ft (backward) / tau (forward)

template<int KMODE>
__device__ __forceinline__ void storeK(void* wsv, size_t of, int l, double X0,double X1,double X2,double X3){
  if (KMODE==0){
    float* wsb=(float*)wsv + of*52;
    if (l<12)       ((float4*)wsb)[l]  = make_float4((float)X0,(float)X1,(float)X2,(float)X3);
    else if (l==12) ((float4*)wsb)[12] = make_float4((float)X0,(float)X1,(float)X2,(float)X3);
  } else {
    __half* wsb=(__half*)wsv + of*52;
    if (l<12){
      wsb[l*4+0]=__float2half((float)X0); wsb[l*4+1]=__float2half((float)X1);
      wsb[l*4+2]=__float2half((float)X2); wsb[l*4+3]=__float2half((float)X3);
    } else if (l==12){
      wsb[48]=__float2half((float)X0); wsb[49]=__float2half((float)X1);
      wsb[50]=__float2half((float)X2); wsb[51]=__float2half((float)X3);
    }
  }
}
template<int KMODE>
__device__ __forceinline__ float4 loadKcol(const void* wsv, size_t of, int l){
  if (KMODE==0) return ((const float4*)((const float*)wsv + of*52))[l];
  const __half* p=(const __half*)wsv + of*52 + l*4;
  return make_float4(__half2float(p[0]),__half2float(p[1]),__half2float(p[2]),__half2float(p[3]));
}
template<int KMODE>
__device__ __forceinline__ float loadkk(const void* wsv, size_t of, int r){
  if (KMODE==0) return ((const float*)wsv)[of*52+48+r];
  return __half2float(((const __half*)wsv)[of*52+48+r]);
}

template<int KMODE>
__global__ __launch_bounds__(256)
void lqr_fused(const float* __restrict__ xinit,
               const float* __restrict__ Cg,
               const float* __restrict__ cg,
               const float* __restrict__ Fg,
               const float* __restrict__ fg,
               float* __restrict__ out,
               void* __restrict__ wsv)
{
  __shared__ double smem[GSTRIDE*16];
  const int tid = threadIdx.x;
  const int g = tid >> 4, l = tid & 15;
  const int b = blockIdx.x*16 + g;
  const int gb = (tid & 63) & ~15;

  double* __restrict__ V   = smem + (size_t)g*GSTRIDE;
  double* __restrict__ S   = V + 144;
  float*  __restrict__ Fl  = (float*)S;          // 12 rows, stride 20 floats
  double* __restrict__ Qxu = V + 288;
  double* __restrict__ Quu = V + 336;
  double* __restrict__ vv  = V + 352;
  double* __restrict__ tb  = V + 364;

  if (l < 12){
    #pragma unroll
    for (int i=0;i<12;i++) V[i*12+l]=0.0;
    vv[l]=0.0;
  }

  // ---------------- backward Riccati (fp64) ----------------
  float4 sC0,sC1,sC2,sC3; float sc_;
  float4 sF0=make_float4(0,0,0,0),sF1=sF0,sF2=sF0,sF3=sF0; float sf_=0.f;
  {
    const size_t of = ((size_t)(TT-1)*BB + b);
    const float4* pc = (const float4*)(Cg + of*256 + l*16);
    sC0=pc[0];sC1=pc[1];sC2=pc[2];sC3=pc[3];
    sc_ = cg[of*16 + l];
  }

  for (int tt=TT-1; tt>=0; --tt){
    const bool hasF = (tt < TT-1);
    float4 C0=sC0,C1=sC1,C2=sC2,C3=sC3; float rc=sc_;
    float4 F0=sF0,F1=sF1,F2=sF2,F3=sF3; float rf=sf_;

    if (hasF && l<12){
      float4* q=(float4*)(Fl + l*20);
      q[0]=F0;q[1]=F1;q[2]=F2;q[3]=F3;
      tb[l]=(double)rf;
    }
    __syncthreads(); // B1: Fl/tb staged; prev-iter V/vv writes visible

    if (tt>0){
      const size_t of = ((size_t)(tt-1)*BB + b);
      const float4* pc=(const float4*)(Cg + of*256 + l*16);
      sC0=pc[0];sC1=pc[1];sC2=pc[2];sC3=pc[3];
      sc_=cg[of*16+l];
      if (l<12){
        const float4* pf=(const float4*)(Fg + of*192 + l*16);
        sF0=pf[0];sF1=pf[1];sF2=pf[2];sF3=pf[3];
        sf_=fg[of*12+l];
      }
    }

    double Qc[16] = {(double)C0.x,(double)C0.y,(double)C0.z,(double)C0.w,
                     (double)C1.x,(double)C1.y,(double)C1.z,(double)C1.w,
                     (double)C2.x,(double)C2.y,(double)C2.z,(double)C2.w,
                     (double)C3.x,(double)C3.y,(double)C3.z,(double)C3.w};
    double qv = (double)rc;

    if (hasF){
      double Ftj[12], W[12];
      #pragma unroll
      for (int s=0;s<12;s++) Ftj[s]=(double)Fl[s*20+l];
      #pragma unroll
      for (int s=0;s<12;s++){
        const double2* vr=(const double2*)(V+s*12);
        double2 v0=vr[0],v1=vr[1],v2=vr[2],v3=vr[3],v4=vr[4],v5=vr[5];
        W[s]= v0.x*Ftj[0]+v0.y*Ftj[1]+v1.x*Ftj[2]+v1.y*Ftj[3]
            + v2.x*Ftj[4]+v2.y*Ftj[5]+v3.x*Ftj[6]+v3.y*Ftj[7]
            + v4.x*Ftj[8]+v4.y*Ftj[9]+v5.x*Ftj[10]+v5.y*Ftj[11];
      }
      #pragma unroll
      for (int s=0;s<12;s++){
        const float4* fr=(const float4*)(Fl + s*20);
        float4 f0=fr[0],f1=fr[1],f2=fr[2],f3=fr[3];
        double w=W[s];
        Qc[0]+=(double)f0.x*w;  Qc[1]+=(double)f0.y*w;  Qc[2]+=(double)f0.z*w;  Qc[3]+=(double)f0.w*w;
        Qc[4]+=(double)f1.x*w;  Qc[5]+=(double)f1.y*w;  Qc[6]+=(double)f1.z*w;  Qc[7]+=(double)f1.w*w;
        Qc[8]+=(double)f2.x*w;  Qc[9]+=(double)f2.y*w;  Qc[10]+=(double)f2.z*w; Qc[11]+=(double)f2.w*w;
        Qc[12]+=(double)f3.x*w; Qc[13]+=(double)f3.y*w; Qc[14]+=(double)f3.z*w; Qc[15]+=(double)f3.w*w;
      }
      #pragma unroll
      for (int t2=0;t2<12;t2++) qv += W[t2]*tb[t2];
      #pragma unroll
      for (int s=0;s<12;s++) qv += Ftj[s]*vv[s];
    }

    if (l>=12){
      const int cc=l-12;
      #pragma unroll
      for (int r=0;r<4;r++) Quu[cc*4+r]=Qc[12+r];
      #pragma unroll
      for (int i=0;i<12;i++) Qxu[cc*12+i]=Qc[i];
    }
    __syncthreads(); // B2: Quu/Qxu staged

    double qu0=__shfl(qv,gb+12,64),qu1=__shfl(qv,gb+13,64),
           qu2=__shfl(qv,gb+14,64),qu3=__shfl(qv,gb+15,64);
    double b0,b1,b2,b3;
    if (l<12){b0=-Qc[12];b1=-Qc[13];b2=-Qc[14];b3=-Qc[15];}
    else     {b0=-qu0;b1=-qu1;b2=-qu2;b3=-qu3;}

    double a00=Quu[0],a10=Quu[1],a20=Quu[2],a30=Quu[3];
    double a01=Quu[4],a11=Quu[5],a21=Quu[6],a31=Quu[7];
    double a02=Quu[8],a12=Quu[9],a22=Quu[10],a32=Quu[11];
    double a03=Quu[12],a13=Quu[13],a23=Quu[14],a33=Quu[15];

    // 4x4 LU, no pivot (Quu SPD, pivots >= lambda_min(Cuu) >= 1)
    double m10=a10/a00,m20=a20/a00,m30=a30/a00;
    a11-=m10*a01;a12-=m10*a02;a13-=m10*a03;b1-=m10*b0;
    a21-=m20*a01;a22-=m20*a02;a23-=m20*a03;b2-=m20*b0;
    a31-=m30*a01;a32-=m30*a02;a33-=m30*a03;b3-=m30*b0;
    double m21=a21/a11,m31=a31/a11;
    a22-=m21*a12;a23-=m21*a13;b2-=m21*b1;
    a32-=m31*a12;a33-=m31*a13;b3-=m31*b1;
    double m32=a32/a22;
    a33-=m32*a23;b3-=m32*b2;
    double X3=b3/a33;
    double X2=(b2-a23*X3)/a22;
    double X1=(b1-a12*X2-a13*X3)/a11;
    double X0=(b0-a01*X1-a02*X2-a03*X3)/a00;

    // k broadcast straight from lane gb+12 (no LDS round-trip)
    double k0=__shfl(X0,gb+12,64),k1=__shfl(X1,gb+12,64),
           k2=__shfl(X2,gb+12,64),k3=__shfl(X3,gb+12,64);

    storeK<KMODE>(wsv, (size_t)tt*BB+b, l, X0,X1,X2,X3);

    double Vn[12];
    if (l<12){
      #pragma unroll
      for (int i=0;i<12;i++) Vn[i]=Qc[i];
      #pragma unroll
      for (int r=0;r<4;r++){
        const double Xr=(r==0)?X0:(r==1)?X1:(r==2)?X2:X3;
        const double2* qx=(const double2*)(Qxu+r*12);
        double2 x0=qx[0],x1=qx[1],x2=qx[2],x3=qx[3],x4=qx[4],x5=qx[5];
        Vn[0]+=x0.x*Xr; Vn[1]+=x0.y*Xr; Vn[2]+=x1.x*Xr;  Vn[3]+=x1.y*Xr;
        Vn[4]+=x2.x*Xr; Vn[5]+=x2.y*Xr; Vn[6]+=x3.x*Xr;  Vn[7]+=x3.y*Xr;
        Vn[8]+=x4.x*Xr; Vn[9]+=x4.y*Xr; Vn[10]+=x5.x*Xr; Vn[11]+=x5.y*Xr;
      }
      #pragma unroll
      for (int i=0;i<12;i++) S[i*12+l]=Vn[i];
    }
    __syncthreads(); // B3: S (=Vn full matrix) staged
    if (l<12){
      double vn = qv + Qxu[0+l]*k0 + Qxu[12+l]*k1 + Qxu[24+l]*k2 + Qxu[36+l]*k3;
      double Vrow[12];
      #pragma unroll
      for (int j=0;j<12;j++) Vrow[j]=S[l*12+j];
      #pragma unroll
      for (int i=0;i<12;i++) V[i*12+l]=0.5*(Vn[i]+Vrow[i]);
      vv[l]=vn;
    }
    __syncthreads(); // B4: V/vv updated; S reads done before next iter's Fl writes
  }

  // ---------------- forward rollout (fp64) ----------------
  double xj = (l<12)? (double)xinit[(size_t)b*12+l] : 0.0;
  double costacc=0.0;

  float4 sK=make_float4(0,0,0,0); float sk_=0.f;
  {
    const float4* pc=(const float4*)(Cg + (size_t)b*256 + l*16);
    sC0=pc[0];sC1=pc[1];sC2=pc[2];sC3=pc[3];
    sc_=cg[(size_t)b*16+l];
    if (l<12){
      const float4* pf=(const float4*)(Fg + (size_t)b*192 + l*16);
      sF0=pf[0];sF1=pf[1];sF2=pf[2];sF3=pf[3];
      sf_=fg[(size_t)b*12+l];
      sK=loadKcol<KMODE>(wsv,(size_t)b,l);
    } else {
      sk_=loadkk<KMODE>(wsv,(size_t)b,l-12);
    }
  }

  for (int t=0;t<TT;t++){
    float4 C0=sC0,C1=sC1,C2=sC2,C3=sC3; float rc=sc_;
    float4 F0=sF0,F1=sF1,F2=sF2,F3=sF3; float rf=sf_;
    float4 K4=sK; float kl=sk_;

    if (t+1<TT){
      const size_t of=((size_t)(t+1)*BB + b);
      const float4* pc=(const float4*)(Cg + of*256 + l*16);
      sC0=pc[0];sC1=pc[1];sC2=pc[2];sC3=pc[3];
      sc_=cg[of*16+l];
      if (l<12) sK=loadKcol<KMODE>(wsv,of,l);
      else      sk_=loadkk<KMODE>(wsv,of,l-12);
      if (t+1<TT-1 && l<12){
        const float4* pf=(const float4*)(Fg + of*192 + l*16);
        sF0=pf[0];sF1=pf[1];sF2=pf[2];sF3=pf[3];
        sf_=fg[of*12+l];
      }
    }

    // u = K x + k  (16-lane group reduction in fp64)
    double pr0=0,pr1=0,pr2=0,pr3=0;
    if (l<12){ pr0=(double)K4.x*xj; pr1=(double)K4.y*xj; pr2=(double)K4.z*xj; pr3=(double)K4.w*xj; }
    #pragma unroll
    for (int m=1;m<16;m<<=1){
      pr0+=__shfl_xor(pr0,m,64); pr1+=__shfl_xor(pr1,m,64);
      pr2+=__shfl_xor(pr2,m,64); pr3+=__shfl_xor(pr3,m,64);
    }
    double tauj;
    if (l<12) tauj=xj;
    else {
      double ur=(l==12)?pr0:(l==13)?pr1:(l==14)?pr2:pr3;
      tauj=ur+(double)kl;
    }
    tb[l]=tauj;
    __syncthreads(); // F1: tau staged

    double tau[16];
    {
      const double2* tp=(const double2*)tb;
      #pragma unroll
      for (int j=0;j<8;j++){ double2 tv=tp[j]; tau[2*j]=tv.x; tau[2*j+1]=tv.y; }
    }
    const float Cr[16]={C0.x,C0.y,C0.z,C0.w,C1.x,C1.y,C1.z,C1.w,
                        C2.x,C2.y,C2.z,C2.w,C3.x,C3.y,C3.z,C3.w};
    double dot=0.0;
    #pragma unroll
    for (int j=0;j<16;j++) dot += (double)Cr[j]*tau[j];
    costacc += tauj*(0.5*dot+(double)rc);

    if (l<12) out[(size_t)t*BB*12 + (size_t)b*12 + l] = (float)xj;
    else      out[(size_t)TT*BB*12 + (size_t)t*BB*4 + (size_t)b*4 + (l-12)] = (float)tauj;

    double xn=xj;
    if (t<TT-1 && l<12){
      const float Fr[16]={F0.x,F0.y,F0.z,F0.w,F1.x,F1.y,F1.z,F1.w,
                          F2.x,F2.y,F2.z,F2.w,F3.x,F3.y,F3.z,F3.w};
      double d2=(double)rf;
      #pragma unroll
      for (int j=0;j<16;j++) d2 += (double)Fr[j]*tau[j];
      xn=d2;
    }
    __syncthreads(); // F2: tau reads done before next iter's tb writes
    xj=xn;
  }

  costacc+=__shfl_xor(costacc,1,64); costacc+=__shfl_xor(costacc,2,64);
  costacc+=__shfl_xor(costacc,4,64); costacc+=__shfl_xor(costacc,8,64);
  if (l==0) out[(size_t)TT*BB*16 + b]=(float)costacc;
}

extern "C" void kernel_launch(void* const* d_in, const int* in_sizes, int n_in,
                              void* d_out, int out_size, void* d_ws, size_t ws_size,
                              hipStream_t stream){
  (void)in_sizes; (void)n_in; (void)out_size;
  const float* xinit=(const float*)d_in[0];
  const float* C    =(const float*)d_in[1];
  const float* c    =(const float*)d_in[2];
  const float* F    =(const float*)d_in[3];
  const float* f    =(const float*)d_in[4];
  const size_t need_f32 = (size_t)TT*BB*52*sizeof(float);   // 85.2 MB
  if (ws_size >= need_f32){
    lqr_fused<0><<<dim3(BB/16), dim3(256), 0, stream>>>(xinit,C,c,F,f,(float*)d_out,d_ws);
  } else {
    lqr_fused<1><<<dim3(BB/16), dim3(256), 0, stream>>>(xinit,C,c,F,f,(float*)d_out,d_ws);
  }
}

// Round 3
// 525.976 us; speedup vs baseline: 1.2079x; 1.2079x over previous
//
#include <hip/hip_runtime.h>
#include <hip/hip_fp16.h>

#define TT 100
#define BB 4096
#define GS 648   // floats per group blob; 648 % 32 == 8 -> bank stagger across groups

// per-group float layout:
//   V   [0,144)     12x12 value matrix, bitwise symmetric
//   Fl  [144,384)   12 rows x stride 20 (F rows, 16 used)
//   S   [384,528)   12x12 symmetrize scratch (NOT aliased with Fl)
//   Qxu [528,576)   Qxu[r*12+i] = Q[i][12+r]
//   Quu [576,592)   col-major 4x4
//   vv  [592,604)   v
//   tb  [604,636)   2x16 ping-pong: ft (backward, slot 0) / tau (forward)

__device__ __forceinline__ void bar_lds(){
  // workgroup barrier that drains ONLY lgkmcnt (LDS) — global prefetches stay in flight
  asm volatile("" ::: "memory");
  asm volatile("s_waitcnt lgkmcnt(0)" ::: "memory");
  __builtin_amdgcn_s_barrier();
  asm volatile("" ::: "memory");
}

template<int KMODE>
__device__ __forceinline__ void storeK(void* wsv, size_t of, int l, float X0,float X1,float X2,float X3){
  if (KMODE==0){
    float* wsb=(float*)wsv + of*52;
    if (l<12)       ((float4*)wsb)[l]  = make_float4(X0,X1,X2,X3);
    else if (l==12) ((float4*)wsb)[12] = make_float4(X0,X1,X2,X3);
  } else {
    __half* wsb=(__half*)wsv + of*52;
    if (l<12){
      wsb[l*4+0]=__float2half(X0); wsb[l*4+1]=__float2half(X1);
      wsb[l*4+2]=__float2half(X2); wsb[l*4+3]=__float2half(X3);
    } else if (l==12){
      wsb[48]=__float2half(X0); wsb[49]=__float2half(X1);
      wsb[50]=__float2half(X2); wsb[51]=__float2half(X3);
    }
  }
}
template<int KMODE>
__device__ __forceinline__ float4 loadKcol(const void* wsv, size_t of, int l){
  if (KMODE==0) return ((const float4*)((const float*)wsv + of*52))[l];
  const __half* p=(const __half*)wsv + of*52 + l*4;
  return make_float4(__half2float(p[0]),__half2float(p[1]),__half2float(p[2]),__half2float(p[3]));
}
template<int KMODE>
__device__ __forceinline__ float loadkk(const void* wsv, size_t of, int r){
  if (KMODE==0) return ((const float*)wsv)[of*52+48+r];
  return __half2float(((const __half*)wsv)[of*52+48+r]);
}

template<int KMODE>
__global__ __launch_bounds__(256)
void lqr_fused(const float* __restrict__ xinit,
               const float* __restrict__ Cg,
               const float* __restrict__ cg,
               const float* __restrict__ Fg,
               const float* __restrict__ fg,
               float* __restrict__ out,
               void* __restrict__ wsv)
{
  __shared__ float smem[GS*16];
  const int tid = threadIdx.x;
  const int g = tid >> 4, l = tid & 15;
  const int b = blockIdx.x*16 + g;
  const int gb = (tid & 63) & ~15;

  float* __restrict__ V   = smem + (size_t)g*GS;
  float* __restrict__ Fl  = V + 144;
  float* __restrict__ S   = V + 384;
  float* __restrict__ Qxu = V + 528;
  float* __restrict__ Quu = V + 576;
  float* __restrict__ vv  = V + 592;
  float* __restrict__ tb  = V + 604;   // tb + 16 = second buffer

  if (l < 12){
    #pragma unroll
    for (int i=0;i<12;i++) V[i*12+l]=0.f;
    vv[l]=0.f;
  }

  // ---------------- backward Riccati (fp32) ----------------
  float4 sC0,sC1,sC2,sC3; float sc_;
  float4 sF0=make_float4(0,0,0,0),sF1=sF0,sF2=sF0,sF3=sF0; float sf_=0.f;
  {
    const size_t of = ((size_t)(TT-1)*BB + b);
    const float4* pc = (const float4*)(Cg + of*256 + l*16);
    sC0=pc[0];sC1=pc[1];sC2=pc[2];sC3=pc[3];
    sc_ = cg[of*16 + l];
  }

  for (int tt=TT-1; tt>=0; --tt){
    const bool hasF = (tt < TT-1);
    float4 C0=sC0,C1=sC1,C2=sC2,C3=sC3; float rc=sc_;
    float4 F0=sF0,F1=sF1,F2=sF2,F3=sF3; float rf=sf_;

    if (hasF && l<12){
      float4* q=(float4*)(Fl + l*20);
      q[0]=F0;q[1]=F1;q[2]=F2;q[3]=F3;
      tb[l]=rf;
    }
    bar_lds(); // B1: Fl/tb staged; prev-iter V/vv visible

    if (tt>0){
      const size_t of = ((size_t)(tt-1)*BB + b);
      const float4* pc=(const float4*)(Cg + of*256 + l*16);
      sC0=pc[0];sC1=pc[1];sC2=pc[2];sC3=pc[3];
      sc_=cg[of*16+l];
      if (l<12){
        const float4* pf=(const float4*)(Fg + of*192 + l*16);
        sF0=pf[0];sF1=pf[1];sF2=pf[2];sF3=pf[3];
        sf_=fg[of*12+l];
      }
    }

    float Qc[16] = {C0.x,C0.y,C0.z,C0.w, C1.x,C1.y,C1.z,C1.w,
                    C2.x,C2.y,C2.z,C2.w, C3.x,C3.y,C3.z,C3.w};
    float qv = rc;

    if (hasF){
      float Ftj[12], W[12];
      #pragma unroll
      for (int s=0;s<12;s++) Ftj[s]=Fl[s*20+l];
      #pragma unroll
      for (int s=0;s<12;s++){
        const float4* vr=(const float4*)(V+s*12);
        float4 v0=vr[0],v1=vr[1],v2=vr[2];
        W[s]= v0.x*Ftj[0]+v0.y*Ftj[1]+v0.z*Ftj[2]+v0.w*Ftj[3]
            + v1.x*Ftj[4]+v1.y*Ftj[5]+v1.z*Ftj[6]+v1.w*Ftj[7]
            + v2.x*Ftj[8]+v2.y*Ftj[9]+v2.z*Ftj[10]+v2.w*Ftj[11];
      }
      #pragma unroll
      for (int s=0;s<12;s++){
        const float4* fr=(const float4*)(Fl + s*20);
        float4 f0=fr[0],f1=fr[1],f2=fr[2],f3=fr[3];
        float w=W[s];
        Qc[0]+=f0.x*w;  Qc[1]+=f0.y*w;  Qc[2]+=f0.z*w;  Qc[3]+=f0.w*w;
        Qc[4]+=f1.x*w;  Qc[5]+=f1.y*w;  Qc[6]+=f1.z*w;  Qc[7]+=f1.w*w;
        Qc[8]+=f2.x*w;  Qc[9]+=f2.y*w;  Qc[10]+=f2.z*w; Qc[11]+=f2.w*w;
        Qc[12]+=f3.x*w; Qc[13]+=f3.y*w; Qc[14]+=f3.z*w; Qc[15]+=f3.w*w;
      }
      #pragma unroll
      for (int t2=0;t2<12;t2++) qv += W[t2]*tb[t2];
      #pragma unroll
      for (int s=0;s<12;s++) qv += Ftj[s]*vv[s];
    }

    if (l>=12){
      const int cc=l-12;
      #pragma unroll
      for (int r=0;r<4;r++) Quu[cc*4+r]=Qc[12+r];
      #pragma unroll
      for (int i=0;i<12;i++) Qxu[cc*12+i]=Qc[i];
    }
    bar_lds(); // B2: Quu/Qxu staged

    float qu0=__shfl(qv,gb+12,64),qu1=__shfl(qv,gb+13,64),
          qu2=__shfl(qv,gb+14,64),qu3=__shfl(qv,gb+15,64);
    float b0,b1,b2,b3;
    if (l<12){b0=-Qc[12];b1=-Qc[13];b2=-Qc[14];b3=-Qc[15];}
    else     {b0=-qu0;b1=-qu1;b2=-qu2;b3=-qu3;}

    float a00=Quu[0],a10=Quu[1],a20=Quu[2],a30=Quu[3];
    float a01=Quu[4],a11=Quu[5],a21=Quu[6],a31=Quu[7];
    float a02=Quu[8],a12=Quu[9],a22=Quu[10],a32=Quu[11];
    float a03=Quu[12],a13=Quu[13],a23=Quu[14],a33=Quu[15];

    // 4x4 LU, no pivot (Quu SPD, diag >= 1)
    float i0=1.0f/a00;
    float m10=a10*i0,m20=a20*i0,m30=a30*i0;
    a11-=m10*a01;a12-=m10*a02;a13-=m10*a03;b1-=m10*b0;
    a21-=m20*a01;a22-=m20*a02;a23-=m20*a03;b2-=m20*b0;
    a31-=m30*a01;a32-=m30*a02;a33-=m30*a03;b3-=m30*b0;
    float i1=1.0f/a11;
    float m21=a21*i1,m31=a31*i1;
    a22-=m21*a12;a23-=m21*a13;b2-=m21*b1;
    a32-=m31*a12;a33-=m31*a13;b3-=m31*b1;
    float i2=1.0f/a22;
    float m32=a32*i2;
    a33-=m32*a23;b3-=m32*b2;
    float X3=b3/a33;
    float X2=(b2-a23*X3)*i2;
    float X1=(b1-a12*X2-a13*X3)*i1;
    float X0=(b0-a01*X1-a02*X2-a03*X3)*i0;

    // k broadcast straight from lane gb+12
    float k0=__shfl(X0,gb+12,64),k1=__shfl(X1,gb+12,64),
          k2=__shfl(X2,gb+12,64),k3=__shfl(X3,gb+12,64);

    storeK<KMODE>(wsv, (size_t)tt*BB+b, l, X0,X1,X2,X3);

    float Vn[12];
    if (l<12){
      #pragma unroll
      for (int i=0;i<12;i++) Vn[i]=Qc[i];
      #pragma unroll
      for (int r=0;r<4;r++){
        const float Xr=(r==0)?X0:(r==1)?X1:(r==2)?X2:X3;
        const float4* qx=(const float4*)(Qxu+r*12);
        float4 x0=qx[0],x1=qx[1],x2=qx[2];
        Vn[0]+=x0.x*Xr; Vn[1]+=x0.y*Xr; Vn[2]+=x0.z*Xr;  Vn[3]+=x0.w*Xr;
        Vn[4]+=x1.x*Xr; Vn[5]+=x1.y*Xr; Vn[6]+=x1.z*Xr;  Vn[7]+=x1.w*Xr;
        Vn[8]+=x2.x*Xr; Vn[9]+=x2.y*Xr; Vn[10]+=x2.z*Xr; Vn[11]+=x2.w*Xr;
      }
      #pragma unroll
      for (int i=0;i<12;i++) S[i*12+l]=Vn[i];
    }
    bar_lds(); // B3: S staged

    if (l<12){
      float vn = qv + Qxu[0+l]*k0 + Qxu[12+l]*k1 + Qxu[24+l]*k2 + Qxu[36+l]*k3;
      const float4* sr=(const float4*)(S + l*12);
      float4 r0=sr[0],r1=sr[1],r2=sr[2];
      V[0*12+l]=0.5f*(Vn[0]+r0.x);   V[1*12+l]=0.5f*(Vn[1]+r0.y);
      V[2*12+l]=0.5f*(Vn[2]+r0.z);   V[3*12+l]=0.5f*(Vn[3]+r0.w);
      V[4*12+l]=0.5f*(Vn[4]+r1.x);   V[5*12+l]=0.5f*(Vn[5]+r1.y);
      V[6*12+l]=0.5f*(Vn[6]+r1.z);   V[7*12+l]=0.5f*(Vn[7]+r1.w);
      V[8*12+l]=0.5f*(Vn[8]+r2.x);   V[9*12+l]=0.5f*(Vn[9]+r2.y);
      V[10*12+l]=0.5f*(Vn[10]+r2.z); V[11*12+l]=0.5f*(Vn[11]+r2.w);
      vv[l]=vn;
    }
    // no B4: next write to S is after next iter's B2; V/vv reads gated by next B1
  }

  // drain K/k stores before forward reads them (cross-lane global RAW at t=0)
  asm volatile("s_waitcnt vmcnt(0)" ::: "memory");

  // ---------------- forward rollout (fp32, fp64 cost accum) ----------------
  float xj = (l<12)? xinit[(size_t)b*12+l] : 0.f;
  double costacc=0.0;

  float4 sK=make_float4(0,0,0,0); float sk_=0.f;
  {
    const float4* pc=(const float4*)(Cg + (size_t)b*256 + l*16);
    sC0=pc[0];sC1=pc[1];sC2=pc[2];sC3=pc[3];
    sc_=cg[(size_t)b*16+l];
    if (l<12){
      const float4* pf=(const float4*)(Fg + (size_t)b*192 + l*16);
      sF0=pf[0];sF1=pf[1];sF2=pf[2];sF3=pf[3];
      sf_=fg[(size_t)b*12+l];
      sK=loadKcol<KMODE>(wsv,(size_t)b,l);
    } else {
      sk_=loadkk<KMODE>(wsv,(size_t)b,l-12);
    }
  }

  for (int t=0;t<TT;t++){
    float4 C0=sC0,C1=sC1,C2=sC2,C3=sC3; float rc=sc_;
    float4 F0=sF0,F1=sF1,F2=sF2,F3=sF3; float rf=sf_;
    float4 K4=sK; float kl=sk_;

    if (t+1<TT){
      const size_t of=((size_t)(t+1)*BB + b);
      const float4* pc=(const float4*)(Cg + of*256 + l*16);
      sC0=pc[0];sC1=pc[1];sC2=pc[2];sC3=pc[3];
      sc_=cg[of*16+l];
      if (l<12) sK=loadKcol<KMODE>(wsv,of,l);
      else      sk_=loadkk<KMODE>(wsv,of,l-12);
      if (t+1<TT-1 && l<12){
        const float4* pf=(const float4*)(Fg + of*192 + l*16);
        sF0=pf[0];sF1=pf[1];sF2=pf[2];sF3=pf[3];
        sf_=fg[of*12+l];
      }
    }

    // u = K x + k (16-lane group reduction)
    float pr0=0.f,pr1=0.f,pr2=0.f,pr3=0.f;
    if (l<12){ pr0=K4.x*xj; pr1=K4.y*xj; pr2=K4.z*xj; pr3=K4.w*xj; }
    #pragma unroll
    for (int m=1;m<16;m<<=1){
      pr0+=__shfl_xor(pr0,m,64); pr1+=__shfl_xor(pr1,m,64);
      pr2+=__shfl_xor(pr2,m,64); pr3+=__shfl_xor(pr3,m,64);
    }
    float tauj;
    if (l<12) tauj=xj;
    else {
      float ur=(l==12)?pr0:(l==13)?pr1:(l==14)?pr2:pr3;
      tauj=ur+kl;
    }
    float* tbuf = tb + (t&1)*16;   // ping-pong: no trailing barrier needed
    tbuf[l]=tauj;
    bar_lds(); // F1: tau staged

    float4 t0=((const float4*)tbuf)[0], t1v=((const float4*)tbuf)[1],
           t2v=((const float4*)tbuf)[2], t3v=((const float4*)tbuf)[3];

    const float Cr[16]={C0.x,C0.y,C0.z,C0.w,C1.x,C1.y,C1.z,C1.w,
                        C2.x,C2.y,C2.z,C2.w,C3.x,C3.y,C3.z,C3.w};
    const float ta[16]={t0.x,t0.y,t0.z,t0.w,t1v.x,t1v.y,t1v.z,t1v.w,
                        t2v.x,t2v.y,t2v.z,t2v.w,t3v.x,t3v.y,t3v.z,t3v.w};
    float dot=0.f;
    #pragma unroll
    for (int j=0;j<16;j++) dot += Cr[j]*ta[j];
    costacc += (double)(tauj*(0.5f*dot+rc));

    if (l<12) out[(size_t)t*BB*12 + (size_t)b*12 + l] = xj;
    else      out[(size_t)TT*BB*12 + (size_t)t*BB*4 + (size_t)b*4 + (l-12)] = tauj;

    if (t<TT-1 && l<12){
      const float Fr[16]={F0.x,F0.y,F0.z,F0.w,F1.x,F1.y,F1.z,F1.w,
                          F2.x,F2.y,F2.z,F2.w,F3.x,F3.y,F3.z,F3.w};
      float d2=rf;
      #pragma unroll
      for (int j=0;j<16;j++) d2 += Fr[j]*ta[j];
      xj=d2;
    }
  }

  costacc+=__shfl_xor(costacc,1,64); costacc+=__shfl_xor(costacc,2,64);
  costacc+=__shfl_xor(costacc,4,64); costacc+=__shfl_xor(costacc,8,64);
  if (l==0) out[(size_t)TT*BB*16 + b]=(float)costacc;
}

extern "C" void kernel_launch(void* const* d_in, const int* in_sizes, int n_in,
                              void* d_out, int out_size, void* d_ws, size_t ws_size,
                              hipStream_t stream){
  (void)in_sizes; (void)n_in; (void)out_size;
  const float* xinit=(const float*)d_in[0];
  const float* C    =(const float*)d_in[1];
  const float* c    =(const float*)d_in[2];
  const float* F    =(const float*)d_in[3];
  const float* f    =(const float*)d_in[4];
  const size_t need_f32 = (size_t)TT*BB*52*sizeof(float);   // 85.2 MB
  if (ws_size >= need_f32){
    lqr_fused<0><<<dim3(BB/16), dim3(256), 0, stream>>>(xinit,C,c,F,f,(float*)d_out,d_ws);
  } else {
    lqr_fused<1><<<dim3(BB/16), dim3(256), 0, stream>>>(xinit,C,c,F,f,(float*)d_out,d_ws);
  }
}

// Round 4
// 466.582 us; speedup vs baseline: 1.3617x; 1.1273x over previous
//
#include <hip/hip_runtime.h>
#include <hip/hip_fp16.h>

#define TT 100
#define BB 4096
#define GS 648   // floats per batch blob; 648 % 32 == 8 -> bank stagger

// per-batch float layout:
//   V   [0,144)     12x12 value matrix (bitwise symmetric)
//   Fl  [144,384)   12 rows x stride 20
//   S   [384,528)   12x12 symmetrize scratch
//   Qxu [528,576)   Qxu[r*12+i] = Q[i][12+r]
//   Quu [576,592)   col-major 4x4
//   vv  [592,604)   v
//   tb  [604,636)   ft (backward) / 2x16 tau ping-pong (forward)

// wave-internal LDS fence: batch lives in one wave; no s_barrier needed.
#define FENCE() asm volatile("s_waitcnt lgkmcnt(0)" ::: "memory")

template<int KMODE>
__device__ __forceinline__ void storeK(void* wsv, size_t of, int l, float X0,float X1,float X2,float X3){
  if (KMODE==0){
    float* wsb=(float*)wsv + of*52;
    if (l<12)       ((float4*)wsb)[l]  = make_float4(X0,X1,X2,X3);
    else if (l==12) ((float4*)wsb)[12] = make_float4(X0,X1,X2,X3);
  } else {
    __half* wsb=(__half*)wsv + of*52;
    if (l<12){
      wsb[l*4+0]=__float2half(X0); wsb[l*4+1]=__float2half(X1);
      wsb[l*4+2]=__float2half(X2); wsb[l*4+3]=__float2half(X3);
    } else if (l==12){
      wsb[48]=__float2half(X0); wsb[49]=__float2half(X1);
      wsb[50]=__float2half(X2); wsb[51]=__float2half(X3);
    }
  }
}
template<int KMODE>
__device__ __forceinline__ float4 loadKcol(const void* wsv, size_t of, int l){
  if (KMODE==0) return ((const float4*)((const float*)wsv + of*52))[l];
  const __half* p=(const __half*)wsv + of*52 + l*4;
  return make_float4(__half2float(p[0]),__half2float(p[1]),__half2float(p[2]),__half2float(p[3]));
}
template<int KMODE>
__device__ __forceinline__ float loadkk(const void* wsv, size_t of, int r){
  if (KMODE==0) return ((const float*)wsv)[of*52+48+r];
  return __half2float(((const __half*)wsv)[of*52+48+r]);
}

template<int KMODE>
__global__ __launch_bounds__(256)
void lqr_fused(const float* __restrict__ xinit,
               const float* __restrict__ Cg,
               const float* __restrict__ cg,
               const float* __restrict__ Fg,
               const float* __restrict__ fg,
               float* __restrict__ out,
               void* __restrict__ wsv)
{
  __shared__ float smem[GS*8];
  const int tid  = threadIdx.x;
  const int gi   = tid >> 5;        // batch group in block (0..7)
  const int lane = tid & 63;
  const int l    = tid & 15;        // column
  const int h    = (tid >> 4) & 1;  // half (s/i ranges [6h,6h+6), C rows [8h,8h+8))
  const int b    = blockIdx.x*8 + gi;
  const int gb32 = lane & ~31;      // batch base lane within wave

  float* __restrict__ V   = smem + gi*GS;
  float* __restrict__ Fl  = V + 144;
  float* __restrict__ S   = V + 384;
  float* __restrict__ Qxu = V + 528;
  float* __restrict__ Quu = V + 576;
  float* __restrict__ vv  = V + 592;
  float* __restrict__ tb  = V + 604;

  if (h==0 && l<12){
    #pragma unroll
    for (int i=0;i<12;i++) V[i*12+l]=0.f;
    vv[l]=0.f;
  }

  // ================= backward Riccati =================
  float4 sCa,sCb; float sc_;
  float4 sFa=make_float4(0,0,0,0),sFb=sFa; float sf_=0.f;
  {
    const size_t of = ((size_t)(TT-1)*BB + b);
    const float4* pc = (const float4*)(Cg + of*256 + l*16);
    sCa=pc[2*h]; sCb=pc[2*h+1];      // C col l, rows [8h,8h+8)
    sc_ = cg[of*16 + l];
  }

  for (int tt=TT-1; tt>=0; --tt){
    const bool hasF = (tt < TT-1);
    float4 Ca=sCa,Cb=sCb; float rc=sc_;
    float4 Fa=sFa,Fb=sFb; float rf=sf_;

    if (hasF && l<12){
      float4* q=(float4*)(Fl + l*20);
      q[2*h]=Fa; q[2*h+1]=Fb;        // h0: cols 0-7, h1: cols 8-15 of row l
      if (h==0) tb[l]=rf;
    }
    FENCE(); // B1: Fl/tb staged; prev-iter V/vv visible

    if (tt>0){
      const size_t of = ((size_t)(tt-1)*BB + b);
      const float4* pc=(const float4*)(Cg + of*256 + l*16);
      sCa=pc[2*h]; sCb=pc[2*h+1];
      sc_=cg[of*16+l];
      if (l<12){
        const float4* pf=(const float4*)(Fg + of*192 + l*16);
        sFa=pf[2*h]; sFb=pf[2*h+1];
        if (h==0) sf_=fg[of*12+l];
      }
    }

    // partial Q column (C added on owning half's rows)
    const float R0=Ca.x,R1=Ca.y,R2=Ca.z,R3=Ca.w,R4=Cb.x,R5=Cb.y,R6=Cb.z,R7=Cb.w;
    float Qp[16];
    Qp[0]=h?0.f:R0; Qp[1]=h?0.f:R1; Qp[2]=h?0.f:R2; Qp[3]=h?0.f:R3;
    Qp[4]=h?0.f:R4; Qp[5]=h?0.f:R5; Qp[6]=h?0.f:R6; Qp[7]=h?0.f:R7;
    Qp[8]=h?R0:0.f; Qp[9]=h?R1:0.f; Qp[10]=h?R2:0.f; Qp[11]=h?R3:0.f;
    Qp[12]=h?R4:0.f; Qp[13]=h?R5:0.f; Qp[14]=h?R6:0.f; Qp[15]=h?R7:0.f;
    float qvp = h? 0.f : rc;

    if (hasF){
      float FtL[6], FtH[6];
      #pragma unroll
      for (int k2=0;k2<6;k2++){ FtL[k2]=Fl[k2*20+l]; FtH[k2]=Fl[(6+k2)*20+l]; }
      const int s0=6*h;
      float Wl[6];
      #pragma unroll
      for (int k2=0;k2<6;k2++){
        const float4* vr=(const float4*)(V+(s0+k2)*12);
        float4 v0=vr[0],v1=vr[1],v2=vr[2];
        Wl[k2]= v0.x*FtL[0]+v0.y*FtL[1]+v0.z*FtL[2]+v0.w*FtL[3]
              + v1.x*FtL[4]+v1.y*FtL[5]+v1.z*FtH[0]+v1.w*FtH[1]
              + v2.x*FtH[2]+v2.y*FtH[3]+v2.z*FtH[4]+v2.w*FtH[5];
      }
      #pragma unroll
      for (int k2=0;k2<6;k2++){
        const float4* fr=(const float4*)(Fl + (s0+k2)*20);
        float4 f0=fr[0],f1=fr[1],f2=fr[2],f3=fr[3];
        float w=Wl[k2];
        Qp[0]+=f0.x*w;  Qp[1]+=f0.y*w;  Qp[2]+=f0.z*w;  Qp[3]+=f0.w*w;
        Qp[4]+=f1.x*w;  Qp[5]+=f1.y*w;  Qp[6]+=f1.z*w;  Qp[7]+=f1.w*w;
        Qp[8]+=f2.x*w;  Qp[9]+=f2.y*w;  Qp[10]+=f2.z*w; Qp[11]+=f2.w*w;
        Qp[12]+=f3.x*w; Qp[13]+=f3.y*w; Qp[14]+=f3.z*w; Qp[15]+=f3.w*w;
      }
      #pragma unroll
      for (int k2=0;k2<6;k2++){
        qvp += Wl[k2]*tb[s0+k2];
        const float ftk = h? FtH[k2] : FtL[k2];
        qvp += ftk * vv[s0+k2];
      }
    }

    // rebuild full Q(:,l), q(l) on all 32 lanes of the batch
    float Qc[16];
    #pragma unroll
    for (int i=0;i<16;i++) Qc[i] = Qp[i] + __shfl_xor(Qp[i],16,64);
    float qv = qvp + __shfl_xor(qvp,16,64);

    if (h==0 && l>=12){
      const int cc=l-12;
      #pragma unroll
      for (int r=0;r<4;r++) Quu[cc*4+r]=Qc[12+r];
      #pragma unroll
      for (int i=0;i<12;i++) Qxu[cc*12+i]=Qc[i];
    }
    FENCE(); // B2: Quu/Qxu staged

    float qu0=__shfl(qv,gb32+12,64),qu1=__shfl(qv,gb32+13,64),
          qu2=__shfl(qv,gb32+14,64),qu3=__shfl(qv,gb32+15,64);
    float b0,b1,b2,b3;
    if (l<12){b0=-Qc[12];b1=-Qc[13];b2=-Qc[14];b3=-Qc[15];}
    else     {b0=-qu0;b1=-qu1;b2=-qu2;b3=-qu3;}

    float a00=Quu[0],a10=Quu[1],a20=Quu[2],a30=Quu[3];
    float a01=Quu[4],a11=Quu[5],a21=Quu[6],a31=Quu[7];
    float a02=Quu[8],a12=Quu[9],a22=Quu[10],a32=Quu[11];
    float a03=Quu[12],a13=Quu[13],a23=Quu[14],a33=Quu[15];

    // 4x4 LU, no pivot (Quu SPD, diag >= 1)
    float i0=1.0f/a00;
    float m10=a10*i0,m20=a20*i0,m30=a30*i0;
    a11-=m10*a01;a12-=m10*a02;a13-=m10*a03;b1-=m10*b0;
    a21-=m20*a01;a22-=m20*a02;a23-=m20*a03;b2-=m20*b0;
    a31-=m30*a01;a32-=m30*a02;a33-=m30*a03;b3-=m30*b0;
    float i1=1.0f/a11;
    float m21=a21*i1,m31=a31*i1;
    a22-=m21*a12;a23-=m21*a13;b2-=m21*b1;
    a32-=m31*a12;a33-=m31*a13;b3-=m31*b1;
    float i2=1.0f/a22;
    float m32=a32*i2;
    a33-=m32*a23;b3-=m32*b2;
    float X3=b3/a33;
    float X2=(b2-a23*X3)*i2;
    float X1=(b1-a12*X2-a13*X3)*i1;
    float X0=(b0-a01*X1-a02*X2-a03*X3)*i0;

    if (h==0) storeK<KMODE>(wsv, (size_t)tt*BB+b, l, X0,X1,X2,X3);

    const float k0=__shfl(X0,gb32+12,64),k1=__shfl(X1,gb32+12,64),
                k2=__shfl(X2,gb32+12,64),k3=__shfl(X3,gb32+12,64);

    float Vn[6];
    if (l<12){
      const int i0i=6*h;
      #pragma unroll
      for (int k2=0;k2<6;k2++){
        const int i=i0i+k2;
        float vnk = h? Qc[6+k2] : Qc[k2];
        vnk += Qxu[i]*X0 + Qxu[12+i]*X1 + Qxu[24+i]*X2 + Qxu[36+i]*X3;
        S[i*12+l]=vnk; Vn[k2]=vnk;
      }
    }
    FENCE(); // B3: S staged
    if (l<12){
      const int i0i=6*h;
      #pragma unroll
      for (int k2=0;k2<6;k2++){
        const float sl=S[l*12 + i0i+k2];
        V[(i0i+k2)*12+l]=0.5f*(Vn[k2]+sl);
      }
      if (h==0){
        vv[l] = qv + Qxu[l]*k0 + Qxu[12+l]*k1 + Qxu[24+l]*k2 + Qxu[36+l]*k3;
      }
    }
    // V/vv/S WAR vs next iter handled by in-order LDS pipe + next B1 fence
  }

  // drain K/k stores before forward reads them
  asm volatile("s_waitcnt vmcnt(0)" ::: "memory");

  // ================= forward rollout =================
  float xj = (h==0 && l<12)? xinit[(size_t)b*12+l] : 0.f;
  double costacc=0.0;

  float4 sF0=make_float4(0,0,0,0),sF1=sF0,sF2=sF0,sF3=sF0;
  float4 sK=make_float4(0,0,0,0); float sk_=0.f;
  {
    const float4* pc=(const float4*)(Cg + (size_t)b*256 + l*16);
    sCa=pc[2*h]; sCb=pc[2*h+1];
    sc_=cg[(size_t)b*16+l];
    if (h==0 && l<12){
      const float4* pf=(const float4*)(Fg + (size_t)b*192 + l*16);
      sF0=pf[0];sF1=pf[1];sF2=pf[2];sF3=pf[3];
      sf_=fg[(size_t)b*12+l];
      sK=loadKcol<KMODE>(wsv,(size_t)b,l);
    }
    if (h==0 && l>=12) sk_=loadkk<KMODE>(wsv,(size_t)b,l-12);
  }

  for (int t=0;t<TT;t++){
    float4 Ca=sCa,Cb=sCb; float rc=sc_;
    float4 F0=sF0,F1=sF1,F2=sF2,F3=sF3; float rf=sf_;
    float4 K4=sK; float kl=sk_;

    if (t+1<TT){
      const size_t of=((size_t)(t+1)*BB + b);
      const float4* pc=(const float4*)(Cg + of*256 + l*16);
      sCa=pc[2*h]; sCb=pc[2*h+1];
      sc_=cg[of*16+l];
      if (h==0 && l<12){
        sK=loadKcol<KMODE>(wsv,of,l);
        if (t+1<TT-1){
          const float4* pf=(const float4*)(Fg + of*192 + l*16);
          sF0=pf[0];sF1=pf[1];sF2=pf[2];sF3=pf[3];
          sf_=fg[of*12+l];
        }
      }
      if (h==0 && l>=12) sk_=loadkk<KMODE>(wsv,of,l-12);
    }

    // u = K x + k (reduction within h=0's 16-lane subgroup)
    float pr0=0.f,pr1=0.f,pr2=0.f,pr3=0.f;
    if (h==0 && l<12){ pr0=K4.x*xj; pr1=K4.y*xj; pr2=K4.z*xj; pr3=K4.w*xj; }
    #pragma unroll
    for (int m=1;m<16;m<<=1){
      pr0+=__shfl_xor(pr0,m,64); pr1+=__shfl_xor(pr1,m,64);
      pr2+=__shfl_xor(pr2,m,64); pr3+=__shfl_xor(pr3,m,64);
    }
    float* tbuf = tb + (t&1)*16;
    float tauj=0.f;
    if (h==0){
      if (l<12) tauj=xj;
      else {
        const float ur=(l==12)?pr0:(l==13)?pr1:(l==14)?pr2:pr3;
        tauj=ur+kl;
      }
      tbuf[l]=tauj;
    }
    FENCE(); // tau staged

    const float4* tp=(const float4*)tbuf;
    const float4 ta=tp[2*h], tb4=tp[2*h+1];   // tau rows [8h,8h+8)
    const float taul = tbuf[l];

    // cost partial: 0.5 * tau_l * sum_{j in half} C[j][l] tau_j  (+ c_l tau_l on h0)
    float dot_p = Ca.x*ta.x + Ca.y*ta.y + Ca.z*ta.z + Ca.w*ta.w
                + Cb.x*tb4.x + Cb.y*tb4.y + Cb.z*tb4.z + Cb.w*tb4.w;
    costacc += (double)( taul*0.5f*dot_p + (h==0 ? taul*rc : 0.f) );

    if (h==0){
      if (l<12) out[(size_t)t*BB*12 + (size_t)b*12 + l] = xj;
      else      out[(size_t)TT*BB*12 + (size_t)t*BB*4 + (size_t)b*4 + (l-12)] = tauj;
    }

    if (t<TT-1 && h==0 && l<12){
      const float4 t0=tp[0],t1=tp[1],t2=tp[2],t3=tp[3];
      xj = rf
         + F0.x*t0.x+F0.y*t0.y+F0.z*t0.z+F0.w*t0.w
         + F1.x*t1.x+F1.y*t1.y+F1.z*t1.z+F1.w*t1.w
         + F2.x*t2.x+F2.y*t2.y+F2.z*t2.z+F2.w*t2.w
         + F3.x*t3.x+F3.y*t3.y+F3.z*t3.z+F3.w*t3.w;
    }
    // tau WAR across iters: ping-pong buffer
  }

  costacc+=__shfl_xor(costacc,1,64); costacc+=__shfl_xor(costacc,2,64);
  costacc+=__shfl_xor(costacc,4,64); costacc+=__shfl_xor(costacc,8,64);
  costacc+=__shfl_xor(costacc,16,64);
  if (h==0 && l==0) out[(size_t)TT*BB*16 + b]=(float)costacc;
}

extern "C" void kernel_launch(void* const* d_in, const int* in_sizes, int n_in,
                              void* d_out, int out_size, void* d_ws, size_t ws_size,
                              hipStream_t stream){
  (void)in_sizes; (void)n_in; (void)out_size;
  const float* xinit=(const float*)d_in[0];
  const float* C    =(const float*)d_in[1];
  const float* c    =(const float*)d_in[2];
  const float* F    =(const float*)d_in[3];
  const float* f    =(const float*)d_in[4];
  const size_t need_f32 = (size_t)TT*BB*52*sizeof(float);   // 85.2 MB
  if (ws_size >= need_f32){
    lqr_fused<0><<<dim3(BB/8), dim3(256), 0, stream>>>(xinit,C,c,F,f,(float*)d_out,d_ws);
  } else {
    lqr_fused<1><<<dim3(BB/8), dim3(256), 0, stream>>>(xinit,C,c,F,f,(float*)d_out,d_ws);
  }
}